// Round 2
// baseline (401.649 us; speedup 1.0000x reference)
//
#include <hip/hip_runtime.h>

#define BLK 256

// 4 elements per thread. 8 consecutive lanes = one 32-element scale block.
// Outputs (flat fp32): y[N] | codes[N] | scales[N/32] | shifted_bounds[7] | weights[8N]
// Weights region base is == 3 (mod 4) floats, so each thread's contiguous
// 32-float slice is written as 1 scalar + 7 float4 + 1 float2 + 1 scalar,
// all naturally aligned. No LDS transpose, no barrier in the hot path.

__device__ __forceinline__ float fast_rcp(float x)  { return __builtin_amdgcn_rcpf(x); }
__device__ __forceinline__ float fast_exp2(float x) { return __builtin_amdgcn_exp2f(x); }

__global__ __launch_bounds__(BLK) void fp4_kernel(
    const float* __restrict__ x,
    const float* __restrict__ delta_raw,
    const float* __restrict__ bounds_base,
    const float* __restrict__ values_table,
    float* __restrict__ out, long long N)
{
    const int tid = threadIdx.x;
    const long long t4 = (long long)blockIdx.x * BLK + tid;   // float4 index

    __shared__ float s_vals[8];
    if (tid < 8) s_vals[tid] = values_table[tid];

    // wave-uniform shifted bounds
    const float ht = 0.5f * tanhf(delta_raw[0]);
    const float C = 14.4269504088896340f;   // 10 / ln(2)  (z/tau in exp2 domain)
    float sb[7], sbC[7];
#pragma unroll
    for (int j = 0; j < 7; ++j) { sb[j] = bounds_base[j] + ht; sbC[j] = sb[j] * C; }

    __syncthreads();

    const float4 xv = reinterpret_cast<const float4*>(x)[t4];
    float xe[4] = {xv.x, xv.y, xv.z, xv.w};

    // per-32-block amax: 4 local + butterfly over 8-lane group
    float a = fmaxf(fmaxf(fabsf(xe[0]), fabsf(xe[1])), fmaxf(fabsf(xe[2]), fabsf(xe[3])));
    a = fmaxf(a, __shfl_xor(a, 1, 8));
    a = fmaxf(a, __shfl_xor(a, 2, 8));
    a = fmaxf(a, __shfl_xor(a, 4, 8));

    // e8m0 scale decision — keep bit-compatible with the reference's fp32 path
    const float descale = a / 6.0f;                         // exact IEEE div
    const float e = ceilf(fmaxf(log2f(descale), -127.0f));
    const float scale = exp2f(e);                           // exact pow2
    const float inv_scale = exp2f(-e);                      // exact pow2

    float yv[4], cv[4], wbuf[32];

#pragma unroll
    for (int i = 0; i < 4; ++i) {
        const float xs = xe[i] * inv_scale;   // == xe/scale exactly (pow2)
        const float xa = fabsf(xs);

        int ord = 0;
        float p[7];
#pragma unroll
        for (int j = 0; j < 7; ++j) {
            // sigmoid((xa-sb)/0.1) = 1/(1+2^(sbC - xa*C))
            p[j] = fast_rcp(1.0f + fast_exp2(fmaf(xa, -C, sbC[j])));
            ord += (xa > sb[j]) ? 1 : 0;
        }

        float w[8];
        w[0] = 1.0f - p[0];
#pragma unroll
        for (int j = 1; j < 7; ++j) w[j] = p[j - 1] - p[j];
        w[7] = p[6];

        float sum = 0.0f;
#pragma unroll
        for (int k = 0; k < 8; ++k) { w[k] = fmaxf(w[k], 0.0f); sum += w[k]; }
        const float inv = fast_rcp(sum + 1e-8f);

        float abs_soft = 0.0f;
#pragma unroll
        for (int k = 0; k < 8; ++k) { w[k] *= inv; abs_soft += w[k] * s_vals[k]; }

        const float abs_hard = s_vals[ord];
        const float abs_mix = abs_soft + (abs_hard - abs_soft);  // faithful ST expr
        const float ys = (xs >= 0.0f) ? abs_mix : -abs_mix;

        yv[i] = ys * scale;
        cv[i] = (float)(((xs < 0.0f) ? 8 : 0) | ord);
#pragma unroll
        for (int k = 0; k < 8; ++k) wbuf[i * 8 + k] = w[k];
    }

    // ---- stores ----
    reinterpret_cast<float4*>(out)[t4] = make_float4(yv[0], yv[1], yv[2], yv[3]);
    reinterpret_cast<float4*>(out + N)[t4] = make_float4(cv[0], cv[1], cv[2], cv[3]);

    if ((tid & 7) == 0) out[2 * N + (t4 >> 3)] = e + 127.0f;   // 8 contiguous/wave
    if (blockIdx.x == 0 && tid < 7) out[2 * N + (N >> 5) + tid] = sb[tid];

    // weights: contiguous 32-float slice at wb (== 3 mod 4 floats)
    const long long wb = 2 * N + (N >> 5) + 7 + 32 * t4;
    out[wb] = wbuf[0];
    float* wp = out + wb + 1;                 // 16B-aligned
#pragma unroll
    for (int k = 0; k < 7; ++k)
        reinterpret_cast<float4*>(wp)[k] =
            make_float4(wbuf[4 * k + 1], wbuf[4 * k + 2], wbuf[4 * k + 3], wbuf[4 * k + 4]);
    reinterpret_cast<float2*>(out + wb + 29)[0] = make_float2(wbuf[29], wbuf[30]);
    out[wb + 31] = wbuf[31];
}

extern "C" void kernel_launch(void* const* d_in, const int* in_sizes, int n_in,
                              void* d_out, int out_size, void* d_ws, size_t ws_size,
                              hipStream_t stream) {
    const float* x      = (const float*)d_in[0];
    const float* delta  = (const float*)d_in[1];
    const float* bounds = (const float*)d_in[2];
    const float* vals   = (const float*)d_in[3];
    float* out = (float*)d_out;
    const long long N = (long long)in_sizes[0];   // 8388608
    const int nblocks = (int)(N / (4 * BLK));     // 8192
    fp4_kernel<<<nblocks, BLK, 0, stream>>>(x, delta, bounds, vals, out, N);
}